// Round 7
// baseline (591.583 us; speedup 1.0000x reference)
//
#include <hip/hip_runtime.h>
#include <hip/hip_bf16.h>
#include <cstddef>

// Problem dims
#define H   512
#define E   256
#define V   32000
#define L   1024
#define B   64
#define KX  768      // E + H
#define M_TOT 65536  // L*B

typedef __attribute__((ext_vector_type(8))) _Float16 half8v;
typedef __attribute__((ext_vector_type(4))) float f32x4;

// ---------------------------------------------------------------------------
// K-1: convert W_attn[:, H:] to fp16 once (512 KB out).
// ---------------------------------------------------------------------------
__global__ __launch_bounds__(256) void k_conv_w(const float* __restrict__ W_attn,
                                                unsigned short* __restrict__ Wf) {
    int e0 = blockIdx.x * 2048 + threadIdx.x * 8;      // 0..262143
    int j = e0 >> 9, k = e0 & 511;
    const float* src = &W_attn[(size_t)j * (2 * H) + H + k];
    float4 x0 = *reinterpret_cast<const float4*>(src);
    float4 x1 = *reinterpret_cast<const float4*>(src + 4);
    float xs[8] = {x0.x, x0.y, x0.z, x0.w, x1.x, x1.y, x1.z, x1.w};
    union { half8v v; _Float16 u[8]; } hv;
    #pragma unroll
    for (int i = 0; i < 8; ++i) hv.u[i] = (_Float16)xs[i];
    *reinterpret_cast<half8v*>(&Wf[e0]) = hv.v;
}

// ---------------------------------------------------------------------------
// K0: build xprevT[k][b]
// ---------------------------------------------------------------------------
__global__ __launch_bounds__(256) void k_build(const int* __restrict__ inp,
                                               const float* __restrict__ loc,
                                               const float* __restrict__ hprev,
                                               const float* __restrict__ emb,
                                               float* __restrict__ xprevT) {
    int gid = blockIdx.x * 256 + threadIdx.x;
    int k = gid >> 6, b = gid & 63;
    float v;
    if (k < 256)      v = emb[(size_t)inp[b] * E + k];
    else if (k < 768) v = loc[b * H + (k - 256)];
    else              v = hprev[b * H + (k - 768)];
    xprevT[gid] = v;
}

// ---------------------------------------------------------------------------
// K1: LSTM cell (fp32)
// ---------------------------------------------------------------------------
__global__ __launch_bounds__(256) void k_lstm(const float* __restrict__ W_ih,
                                              const float* __restrict__ W_hh,
                                              const float* __restrict__ b_ih,
                                              const float* __restrict__ b_hh,
                                              const float* __restrict__ xprevT,
                                              const float* __restrict__ cprev,
                                              float* __restrict__ h_out,
                                              float* __restrict__ c_out,
                                              float* __restrict__ hnewT) {
    int u = blockIdx.x;
    int w = threadIdx.x >> 6;
    int b = threadIdx.x & 63;
    int j = w * 512 + u;
    float a0 = 0.f, a1 = 0.f, a2 = 0.f, a3 = 0.f;
    const float* Wr = &W_ih[(size_t)j * KX];
    for (int k = 0; k < KX; k += 4) {
        float4 wv = *reinterpret_cast<const float4*>(&Wr[k]);
        a0 += wv.x * xprevT[(k + 0) * 64 + b];
        a1 += wv.y * xprevT[(k + 1) * 64 + b];
        a2 += wv.z * xprevT[(k + 2) * 64 + b];
        a3 += wv.w * xprevT[(k + 3) * 64 + b];
    }
    const float* Wr2 = &W_hh[(size_t)j * H];
    const float* hT = &xprevT[KX * 64];
    for (int k = 0; k < H; k += 4) {
        float4 wv = *reinterpret_cast<const float4*>(&Wr2[k]);
        a0 += wv.x * hT[(k + 0) * 64 + b];
        a1 += wv.y * hT[(k + 1) * 64 + b];
        a2 += wv.z * hT[(k + 2) * 64 + b];
        a3 += wv.w * hT[(k + 3) * 64 + b];
    }
    float acc = b_ih[j] + b_hh[j] + ((a0 + a1) + (a2 + a3));
    __shared__ float gs[4][64];
    gs[w][b] = acc;
    __syncthreads();
    if (threadIdx.x < 64) {
        float ig = 1.f / (1.f + __expf(-gs[0][b]));
        float fg = 1.f / (1.f + __expf(-gs[1][b]));
        float gg = tanhf(gs[2][b]);
        float og = 1.f / (1.f + __expf(-gs[3][b]));
        float c = fg * cprev[b * H + u] + ig * gg;
        float h = og * tanhf(c);
        c_out[b * H + u] = c;
        h_out[b * H + u] = h;
        hnewT[u * 64 + b] = h;
    }
}

// ---------------------------------------------------------------------------
// K2: hW_jb[j][b] = b_attn[j] + sum_k h[b][k] * W_attn[j][k]
// ---------------------------------------------------------------------------
__global__ __launch_bounds__(256) void k_hw(const float* __restrict__ W_attn,
                                            const float* __restrict__ b_attn,
                                            const float* __restrict__ hT,
                                            float* __restrict__ hW_jb) {
    int j = blockIdx.x * 4 + (threadIdx.x >> 6);
    int b = threadIdx.x & 63;
    float a0 = 0.f, a1 = 0.f, a2 = 0.f, a3 = 0.f;
    const float* Wr = &W_attn[(size_t)j * (2 * H)];
    for (int k = 0; k < H; k += 4) {
        float4 wv = *reinterpret_cast<const float4*>(&Wr[k]);
        a0 += wv.x * hT[(k + 0) * 64 + b];
        a1 += wv.y * hT[(k + 1) * 64 + b];
        a2 += wv.z * hT[(k + 2) * 64 + b];
        a3 += wv.w * hT[(k + 3) * 64 + b];
    }
    hW_jb[j * 64 + b] = b_attn[j] + ((a0 + a1) + (a2 + a3));
}

// ---------------------------------------------------------------------------
// K3: energy GEMM, fp16 MFMA, BK=64, XCD-aware block swizzle.
// grid 2048; xcd = bid&7 owns mt range [xcd*64, xcd*64+64); the 4 jt-siblings
// of one mt are consecutive on the same XCD -> enc tile L2-resident.
// Output: partial_e[jt][m] = sum_{j in tile} tanh(C+hW)*beta.
// ---------------------------------------------------------------------------
#define BKE 64
#define PITCHE 72

__global__ __launch_bounds__(256, 4) void k_energy_v5(
        const float* __restrict__ enc,
        const unsigned short* __restrict__ Wf,
        const float* __restrict__ hW,
        const float* __restrict__ beta,
        float* __restrict__ partial_e) {
    __shared__ unsigned short Ah[128 * PITCHE];
    __shared__ unsigned short Bh[128 * PITCHE];
    __shared__ float red[2][128];

    const int tid  = threadIdx.x;
    const int lane = tid & 63;
    const int wave = tid >> 6;
    const int wm = wave >> 1;
    const int wn = wave & 1;
    // XCD-aware swizzle (bijective: 2048 % 8 == 0)
    const int bid = blockIdx.x;
    const int xcd = bid & 7;
    const int loc = bid >> 3;            // 0..255 within XCD
    const int mt  = xcd * 64 + (loc >> 2);
    const int jt  = loc & 3;
    const int m0 = mt * 128;
    const int j0 = jt * 128;

    const int q  = tid & 7;              // col group (8 cols)
    const int r0 = tid >> 3;             // 0..31; rows r0 + 32p

    float4 ra0[4], ra1[4];               // next A tile (fp32), 4 rows x 8 cols
    half8v rb[4];                        // next B tile (fp16)
    #pragma unroll
    for (int p = 0; p < 4; ++p) {
        int row = p * 32 + r0;
        const float* asrc = &enc[(size_t)(m0 + row) * H + q * 8];
        ra0[p] = *reinterpret_cast<const float4*>(asrc);
        ra1[p] = *reinterpret_cast<const float4*>(asrc + 4);
        rb[p] = *reinterpret_cast<const half8v*>(&Wf[(size_t)(j0 + row) * H + q * 8]);
    }

    f32x4 acc[4][4];
    #pragma unroll
    for (int i = 0; i < 4; ++i)
        #pragma unroll
        for (int j = 0; j < 4; ++j) acc[i][j] = (f32x4){0.f, 0.f, 0.f, 0.f};

    for (int k0 = 0; k0 < H; k0 += BKE) {
        __syncthreads();                 // previous iter's reads done
        #pragma unroll
        for (int p = 0; p < 4; ++p) {
            float xs[8] = {ra0[p].x, ra0[p].y, ra0[p].z, ra0[p].w,
                           ra1[p].x, ra1[p].y, ra1[p].z, ra1[p].w};
            union { half8v v; _Float16 u[8]; } hv;
            #pragma unroll
            for (int i = 0; i < 8; ++i) hv.u[i] = (_Float16)xs[i];
            int off = (p * 32 + r0) * PITCHE + q * 8;
            *reinterpret_cast<half8v*>(&Ah[off]) = hv.v;
            *reinterpret_cast<half8v*>(&Bh[off]) = rb[p];
        }
        __syncthreads();                 // writes visible
        if (k0 + BKE < H) {              // prefetch next tile under the MFMAs
            int kn = k0 + BKE;
            #pragma unroll
            for (int p = 0; p < 4; ++p) {
                int row = p * 32 + r0;
                const float* asrc = &enc[(size_t)(m0 + row) * H + kn + q * 8];
                ra0[p] = *reinterpret_cast<const float4*>(asrc);
                ra1[p] = *reinterpret_cast<const float4*>(asrc + 4);
                rb[p] = *reinterpret_cast<const half8v*>(&Wf[(size_t)(j0 + row) * H + kn + q * 8]);
            }
        }
        const int fr = lane & 15;
        const int kb = (lane >> 4) * 8;
        half8v a_h[4][2], b_h[4][2];
        #pragma unroll
        for (int mf = 0; mf < 4; ++mf) {
            int off = (wm * 64 + mf * 16 + fr) * PITCHE + kb;
            a_h[mf][0] = *reinterpret_cast<const half8v*>(&Ah[off]);
            a_h[mf][1] = *reinterpret_cast<const half8v*>(&Ah[off + 32]);
        }
        #pragma unroll
        for (int nf = 0; nf < 4; ++nf) {
            int off = (wn * 64 + nf * 16 + fr) * PITCHE + kb;
            b_h[nf][0] = *reinterpret_cast<const half8v*>(&Bh[off]);
            b_h[nf][1] = *reinterpret_cast<const half8v*>(&Bh[off + 32]);
        }
        __builtin_amdgcn_s_setprio(1);
        #pragma unroll
        for (int ks = 0; ks < 2; ++ks)
            #pragma unroll
            for (int mf = 0; mf < 4; ++mf)
                #pragma unroll
                for (int nf = 0; nf < 4; ++nf)
                    acc[mf][nf] = __builtin_amdgcn_mfma_f32_16x16x32_f16(
                        a_h[mf][ks], b_h[nf][ks], acc[mf][nf], 0, 0, 0);
        __builtin_amdgcn_s_setprio(0);
    }
    // epilogue: psum[mf][r] = sum_j tanh(C + hW)*beta
    float psum[4][4];
    #pragma unroll
    for (int i = 0; i < 4; ++i)
        #pragma unroll
        for (int r = 0; r < 4; ++r) psum[i][r] = 0.f;
    #pragma unroll
    for (int nf = 0; nf < 4; ++nf) {
        int jj = j0 + wn * 64 + nf * 16 + (lane & 15);
        float bet = beta[jj];
        #pragma unroll
        for (int mf = 0; mf < 4; ++mf) {
            int b_base = (wm * 64 + mf * 16 + (lane >> 4) * 4) & 63;
            float4 hw4 = *reinterpret_cast<const float4*>(&hW[jj * 64 + b_base]);
            float hwv[4] = {hw4.x, hw4.y, hw4.z, hw4.w};
            #pragma unroll
            for (int r = 0; r < 4; ++r) {
                float e = acc[mf][nf][r] + hwv[r];
                float ex = __expf(2.f * e);
                psum[mf][r] += bet * (1.f - 2.f / (ex + 1.f));
            }
        }
    }
    #pragma unroll
    for (int mf = 0; mf < 4; ++mf)
        #pragma unroll
        for (int r = 0; r < 4; ++r) {
            float v = psum[mf][r];
            v += __shfl_xor(v, 1);
            v += __shfl_xor(v, 2);
            v += __shfl_xor(v, 4);
            v += __shfl_xor(v, 8);
            psum[mf][r] = v;
        }
    __syncthreads();
    if ((lane & 15) == 0) {
        #pragma unroll
        for (int mf = 0; mf < 4; ++mf)
            #pragma unroll
            for (int r = 0; r < 4; ++r)
                red[wn][wm * 64 + mf * 16 + (lane >> 4) * 4 + r] = psum[mf][r];
    }
    __syncthreads();
    if (tid < 128)
        partial_e[(size_t)jt * M_TOT + m0 + tid] = red[0][tid] + red[1][tid];
}

// ---------------------------------------------------------------------------
// K4: softmax over l per b.  e[l] = sum_{nb<4} partial_e[nb][l*64+b]
// ---------------------------------------------------------------------------
__global__ __launch_bounds__(256) void k_softmax_l(const float* __restrict__ partial_e,
                                                   float* __restrict__ attn_w) {
    int b = blockIdx.x;
    int tid = threadIdx.x;
    float el[4];
    float m = -1e30f;
    #pragma unroll
    for (int i = 0; i < 4; ++i) {
        int l = i * 256 + tid;
        float e = 0.f;
        #pragma unroll
        for (int nb = 0; nb < 4; ++nb)
            e += partial_e[(size_t)nb * M_TOT + l * 64 + b];
        el[i] = e;
        m = fmaxf(m, e);
    }
    #pragma unroll
    for (int s = 1; s < 64; s <<= 1) m = fmaxf(m, __shfl_xor(m, s));
    __shared__ float redm[4];
    if ((tid & 63) == 0) redm[tid >> 6] = m;
    __syncthreads();
    m = fmaxf(fmaxf(redm[0], redm[1]), fmaxf(redm[2], redm[3]));
    float s = 0.f;
    #pragma unroll
    for (int i = 0; i < 4; ++i) { el[i] = __expf(el[i] - m); s += el[i]; }
    #pragma unroll
    for (int sh = 1; sh < 64; sh <<= 1) s += __shfl_xor(s, sh);
    __shared__ float reds[4];
    if ((tid & 63) == 0) reds[tid >> 6] = s;
    __syncthreads();
    s = reds[0] + reds[1] + reds[2] + reds[3];
    float inv = 1.f / s;
    #pragma unroll
    for (int i = 0; i < 4; ++i)
        attn_w[(i * 256 + tid) * 64 + b] = el[i] * inv;
}

// ---------------------------------------------------------------------------
// K5: context partials over l chunks. float4, 128 threads.
// ---------------------------------------------------------------------------
__global__ __launch_bounds__(128) void k_ctx_part(const float* __restrict__ attn_w,
                                                  const float* __restrict__ enc,
                                                  float* __restrict__ ctx_part) {
    int chunk = blockIdx.x, b = blockIdx.y;
    int h = threadIdx.x * 4;
    float4 acc = {0.f, 0.f, 0.f, 0.f};
    for (int i = 0; i < 32; ++i) {
        int l = chunk * 32 + i;
        float w = attn_w[l * 64 + b];
        float4 e4 = *reinterpret_cast<const float4*>(
            &enc[((size_t)l * 64 + b) * H + h]);
        acc.x += w * e4.x;
        acc.y += w * e4.y;
        acc.z += w * e4.z;
        acc.w += w * e4.w;
    }
    *reinterpret_cast<float4*>(&ctx_part[((size_t)(chunk * 64 + b)) * H + h]) = acc;
}

__global__ __launch_bounds__(256) void k_ctx_reduce(const float* __restrict__ ctx_part,
                                                    float* __restrict__ ctxT) {
    int gid = blockIdx.x * 256 + threadIdx.x;
    int b = gid >> 9, h = gid & 511;
    float s = 0.f;
    for (int c = 0; c < 32; ++c)
        s += ctx_part[((size_t)(c * 64 + b)) * H + h];
    ctxT[h * 64 + b] = s;
}

// ---------------------------------------------------------------------------
// K6: co[b][j] = tanh([h | ctx] . W_oc[j] + b_oc[j])
// ---------------------------------------------------------------------------
__global__ __launch_bounds__(256) void k_co(const float* __restrict__ W_oc,
                                            const float* __restrict__ b_oc,
                                            const float* __restrict__ hT,
                                            const float* __restrict__ ctxT,
                                            float* __restrict__ co_out) {
    int j = blockIdx.x * 4 + (threadIdx.x >> 6);
    int b = threadIdx.x & 63;
    float a0 = 0.f, a1 = 0.f, a2 = 0.f, a3 = 0.f;
    const float* Wr = &W_oc[(size_t)j * (2 * H)];
    for (int k = 0; k < H; k += 4) {
        float4 wv = *reinterpret_cast<const float4*>(&Wr[k]);
        a0 += wv.x * hT[(k + 0) * 64 + b];
        a1 += wv.y * hT[(k + 1) * 64 + b];
        a2 += wv.z * hT[(k + 2) * 64 + b];
        a3 += wv.w * hT[(k + 3) * 64 + b];
    }
    const float* Wr2 = Wr + H;
    for (int k = 0; k < H; k += 4) {
        float4 wv = *reinterpret_cast<const float4*>(&Wr2[k]);
        a0 += wv.x * ctxT[(k + 0) * 64 + b];
        a1 += wv.y * ctxT[(k + 1) * 64 + b];
        a2 += wv.z * ctxT[(k + 2) * 64 + b];
        a3 += wv.w * ctxT[(k + 3) * 64 + b];
    }
    co_out[b * H + j] = tanhf(b_oc[j] + ((a0 + a1) + (a2 + a3)));
}

// ---------------------------------------------------------------------------
// K7: logits GEMM, pure fp16 single-MFMA. grid 500 (64-wide j tiles).
// ---------------------------------------------------------------------------
#define BKL 32
#define PITCHL 40
__global__ __launch_bounds__(256) void k_logits_v2(const float* __restrict__ co,
                                                   const float* __restrict__ W_out,
                                                   const float* __restrict__ b_out,
                                                   float* __restrict__ logits) {
    __shared__ unsigned short Ah[64 * PITCHL];
    __shared__ unsigned short Bh[64 * PITCHL];

    const int tid  = threadIdx.x;
    const int lane = tid & 63;
    const int wave = tid >> 6;
    const int wm = wave >> 1;           // 0..1 : m-half (32 rows)
    const int wn = wave & 1;            // 0..1 : j-half (32 cols)
    const int j0 = blockIdx.x * 64;

    const int srow = tid >> 2;          // 0..63
    const int skc  = tid & 3;           // 0..3

    float4 ra0, ra1, rb0, rb1;
    {
        const float* as = &co[(size_t)srow * H + skc * 8];
        ra0 = *reinterpret_cast<const float4*>(as);
        ra1 = *reinterpret_cast<const float4*>(as + 4);
        const float* bs = &W_out[(size_t)(j0 + srow) * H + skc * 8];
        rb0 = *reinterpret_cast<const float4*>(bs);
        rb1 = *reinterpret_cast<const float4*>(bs + 4);
    }

    f32x4 acc[2][2];
    #pragma unroll
    for (int i = 0; i < 2; ++i)
        #pragma unroll
        for (int j = 0; j < 2; ++j) acc[i][j] = (f32x4){0.f, 0.f, 0.f, 0.f};

    for (int k0 = 0; k0 < H; k0 += BKL) {
        __syncthreads();
        {
            float xs[8] = {ra0.x, ra0.y, ra0.z, ra0.w, ra1.x, ra1.y, ra1.z, ra1.w};
            union { half8v v; _Float16 u[8]; } ha;
            #pragma unroll
            for (int i = 0; i < 8; ++i) ha.u[i] = (_Float16)xs[i];
            float ys[8] = {rb0.x, rb0.y, rb0.z, rb0.w, rb1.x, rb1.y, rb1.z, rb1.w};
            union { half8v v; _Float16 u[8]; } hb;
            #pragma unroll
            for (int i = 0; i < 8; ++i) hb.u[i] = (_Float16)ys[i];
            int off = srow * PITCHL + skc * 8;
            *reinterpret_cast<half8v*>(&Ah[off]) = ha.v;
            *reinterpret_cast<half8v*>(&Bh[off]) = hb.v;
        }
        __syncthreads();
        if (k0 + BKL < H) {
            int kn = k0 + BKL;
            const float* as = &co[(size_t)srow * H + kn + skc * 8];
            ra0 = *reinterpret_cast<const float4*>(as);
            ra1 = *reinterpret_cast<const float4*>(as + 4);
            const float* bs = &W_out[(size_t)(j0 + srow) * H + kn + skc * 8];
            rb0 = *reinterpret_cast<const float4*>(bs);
            rb1 = *reinterpret_cast<const float4*>(bs + 4);
        }
        const int fr = lane & 15;
        const int kb = (lane >> 4) * 8;
        half8v a_h[2], b_h[2];
        #pragma unroll
        for (int mf = 0; mf < 2; ++mf) {
            int off = (wm * 32 + mf * 16 + fr) * PITCHL + kb;
            a_h[mf] = *reinterpret_cast<const half8v*>(&Ah[off]);
        }
        #pragma unroll
        for (int nf = 0; nf < 2; ++nf) {
            int off = (wn * 32 + nf * 16 + fr) * PITCHL + kb;
            b_h[nf] = *reinterpret_cast<const half8v*>(&Bh[off]);
        }
        #pragma unroll
        for (int mf = 0; mf < 2; ++mf)
            #pragma unroll
            for (int nf = 0; nf < 2; ++nf)
                acc[mf][nf] = __builtin_amdgcn_mfma_f32_16x16x32_f16(
                    a_h[mf], b_h[nf], acc[mf][nf], 0, 0, 0);
    }
    #pragma unroll
    for (int nf = 0; nf < 2; ++nf) {
        int j = j0 + wn * 32 + nf * 16 + (lane & 15);
        float bo = b_out[j];
        #pragma unroll
        for (int mf = 0; mf < 2; ++mf) {
            int mbase = wm * 32 + mf * 16 + (lane >> 4) * 4;
            #pragma unroll
            for (int r = 0; r < 4; ++r)
                logits[(size_t)(mbase + r) * V + j] = acc[mf][nf][r] + bo;
        }
    }
}

// ---------------------------------------------------------------------------
// K8a: per-(b, chunk) partial max & expsum. grid (8 chunks, 64 b), 256 thr.
// ---------------------------------------------------------------------------
__global__ __launch_bounds__(256) void k_lsm_part(const float* __restrict__ logits,
                                                  float* __restrict__ pmax,
                                                  float* __restrict__ psum) {
    int chunk = blockIdx.x, b = blockIdx.y;
    int tid = threadIdx.x;
    const float* row = &logits[(size_t)b * V + chunk * 4000];
    float v[16];
    float m = -1e30f;
    #pragma unroll
    for (int t = 0; t < 16; ++t) {
        int i = t * 256 + tid;
        v[t] = (i < 4000) ? row[i] : -1e30f;
        m = fmaxf(m, v[t]);
    }
    #pragma unroll
    for (int s = 1; s < 64; s <<= 1) m = fmaxf(m, __shfl_xor(m, s));
    __shared__ float redm[4];
    if ((tid & 63) == 0) redm[tid >> 6] = m;
    __syncthreads();
    m = fmaxf(fmaxf(redm[0], redm[1]), fmaxf(redm[2], redm[3]));
    float s = 0.f;
    #pragma unroll
    for (int t = 0; t < 16; ++t) s += __expf(v[t] - m);
    #pragma unroll
    for (int sh = 1; sh < 64; sh <<= 1) s += __shfl_xor(s, sh);
    __shared__ float reds[4];
    if ((tid & 63) == 0) reds[tid >> 6] = s;
    __syncthreads();
    if (tid == 0) {
        pmax[chunk * 64 + b] = m;
        psum[chunk * 64 + b] = reds[0] + reds[1] + reds[2] + reds[3];
    }
}

// K8b: lse[b] = gmax + log(sum of rescaled partials). 1 block, 64 threads.
__global__ __launch_bounds__(64) void k_lsm_final(const float* __restrict__ pmax,
                                                  const float* __restrict__ psum,
                                                  float* __restrict__ lse) {
    int b = threadIdx.x;
    float m = -1e30f;
    #pragma unroll
    for (int c = 0; c < 8; ++c) m = fmaxf(m, pmax[c * 64 + b]);
    float s = 0.f;
    #pragma unroll
    for (int c = 0; c < 8; ++c) s += psum[c * 64 + b] * __expf(pmax[c * 64 + b] - m);
    lse[b] = m + __logf(s);
}

// K8c: out = logits - lse[b].  2000 blocks x 256 thr x 4 elems.
__global__ __launch_bounds__(256) void k_lsm_write(const float* __restrict__ logits,
                                                   const float* __restrict__ lse,
                                                   float* __restrict__ out) {
    size_t i4 = ((size_t)blockIdx.x * 256 + threadIdx.x) * 4;
    int b = (int)(i4 / V);
    float l = lse[b];
    float4 x = *reinterpret_cast<const float4*>(&logits[i4]);
    x.x -= l; x.y -= l; x.z -= l; x.w -= l;
    *reinterpret_cast<float4*>(&out[i4]) = x;
}

// ---------------------------------------------------------------------------
extern "C" void kernel_launch(void* const* d_in, const int* in_sizes, int n_in,
                              void* d_out, int out_size, void* d_ws, size_t ws_size,
                              hipStream_t stream) {
    const int*   inp    = (const int*)  d_in[0];
    const float* loc    = (const float*)d_in[1];
    const float* hprev  = (const float*)d_in[2];
    const float* cprev  = (const float*)d_in[3];
    const float* enc    = (const float*)d_in[4];
    const float* emb    = (const float*)d_in[5];
    const float* W_ih   = (const float*)d_in[6];
    const float* W_hh   = (const float*)d_in[7];
    const float* b_ih   = (const float*)d_in[8];
    const float* b_hh   = (const float*)d_in[9];
    const float* W_attn = (const float*)d_in[10];
    const float* b_attn = (const float*)d_in[11];
    const float* beta   = (const float*)d_in[12];
    const float* W_oc   = (const float*)d_in[13];
    const float* b_oc   = (const float*)d_in[14];
    const float* W_out  = (const float*)d_in[15];
    const float* b_out  = (const float*)d_in[16];

    float* out = (float*)d_out;
    float* out_co = out + (size_t)B * V;
    float* out_h  = out_co + B * H;
    float* out_c  = out_h  + B * H;

    float* ws = (float*)d_ws;
    float* xprevT = ws;                                  //    81920
    float* hnewT  = xprevT + 1280 * 64;                  //    32768
    float* hW     = hnewT  + H * 64;                     //    32768
    float* pe     = hW     + H * 64;                     //  4*65536
    float* attnw  = pe     + 4 * M_TOT;                  //    65536
    float* ctxp   = attnw  + M_TOT;                      //  1048576
    float* ctxT   = ctxp   + 32 * 64 * H;                //    32768
    float* logits = ctxT   + H * 64;                     //  2048000
    float* pmax   = logits + (size_t)B * V;              //      512
    float* psum   = pmax   + 512;                        //      512
    float* lse    = psum   + 512;                        //       64
    unsigned short* Wf = (unsigned short*)(lse + 64);    //   262144 u16

    k_conv_w<<<128, 256, 0, stream>>>(W_attn, Wf);
    k_build <<<320, 256, 0, stream>>>(inp, loc, hprev, emb, xprevT);
    k_lstm  <<<512, 256, 0, stream>>>(W_ih, W_hh, b_ih, b_hh, xprevT, cprev,
                                      out_h, out_c, hnewT);
    k_hw    <<<128, 256, 0, stream>>>(W_attn, b_attn, hnewT, hW);
    k_energy_v5<<<2048, 256, 0, stream>>>(enc, Wf, hW, beta, pe);
    k_softmax_l<<<64, 256, 0, stream>>>(pe, attnw);
    k_ctx_part <<<dim3(32, 64), 128, 0, stream>>>(attnw, enc, ctxp);
    k_ctx_reduce<<<128, 256, 0, stream>>>(ctxp, ctxT);
    k_co    <<<128, 256, 0, stream>>>(W_oc, b_oc, hnewT, ctxT, out_co);
    k_logits_v2<<<500, 256, 0, stream>>>(out_co, W_out, b_out, logits);
    k_lsm_part<<<dim3(8, 64), 256, 0, stream>>>(logits, pmax, psum);
    k_lsm_final<<<1, 64, 0, stream>>>(pmax, psum, lse);
    k_lsm_write<<<2000, 256, 0, stream>>>(logits, lse, out);
}

// Round 8
// 313.226 us; speedup vs baseline: 1.8887x; 1.8887x over previous
//
#include <hip/hip_runtime.h>
#include <hip/hip_bf16.h>
#include <cstddef>

// Problem dims
#define H   512
#define E   256
#define V   32000
#define L   1024
#define B   64
#define KX  768      // E + H
#define M_TOT 65536  // L*B

typedef __attribute__((ext_vector_type(8))) _Float16 half8v;
typedef __attribute__((ext_vector_type(4))) float f32x4;

__device__ __forceinline__ half8v cvt8(float4 x0, float4 x1) {
    union { half8v v; _Float16 u[8]; } hv;
    hv.u[0] = (_Float16)x0.x; hv.u[1] = (_Float16)x0.y;
    hv.u[2] = (_Float16)x0.z; hv.u[3] = (_Float16)x0.w;
    hv.u[4] = (_Float16)x1.x; hv.u[5] = (_Float16)x1.y;
    hv.u[6] = (_Float16)x1.z; hv.u[7] = (_Float16)x1.w;
    return hv.v;
}

// ---------------------------------------------------------------------------
// K-1: convert W_attn[:, H:] to fp16 once (512 KB out).
// ---------------------------------------------------------------------------
__global__ __launch_bounds__(256) void k_conv_w(const float* __restrict__ W_attn,
                                                unsigned short* __restrict__ Wf) {
    int e0 = blockIdx.x * 2048 + threadIdx.x * 8;      // 0..262143
    int j = e0 >> 9, k = e0 & 511;
    const float* src = &W_attn[(size_t)j * (2 * H) + H + k];
    float4 x0 = *reinterpret_cast<const float4*>(src);
    float4 x1 = *reinterpret_cast<const float4*>(src + 4);
    half8v hv = cvt8(x0, x1);
    *reinterpret_cast<half8v*>(&Wf[e0]) = hv;
}

// ---------------------------------------------------------------------------
// K0: build xprevT[k][b]
// ---------------------------------------------------------------------------
__global__ __launch_bounds__(256) void k_build(const int* __restrict__ inp,
                                               const float* __restrict__ loc,
                                               const float* __restrict__ hprev,
                                               const float* __restrict__ emb,
                                               float* __restrict__ xprevT) {
    int gid = blockIdx.x * 256 + threadIdx.x;
    int k = gid >> 6, b = gid & 63;
    float v;
    if (k < 256)      v = emb[(size_t)inp[b] * E + k];
    else if (k < 768) v = loc[b * H + (k - 256)];
    else              v = hprev[b * H + (k - 768)];
    xprevT[gid] = v;
}

// ---------------------------------------------------------------------------
// K1: LSTM cell (fp32)
// ---------------------------------------------------------------------------
__global__ __launch_bounds__(256) void k_lstm(const float* __restrict__ W_ih,
                                              const float* __restrict__ W_hh,
                                              const float* __restrict__ b_ih,
                                              const float* __restrict__ b_hh,
                                              const float* __restrict__ xprevT,
                                              const float* __restrict__ cprev,
                                              float* __restrict__ h_out,
                                              float* __restrict__ c_out,
                                              float* __restrict__ hnewT) {
    int u = blockIdx.x;
    int w = threadIdx.x >> 6;
    int b = threadIdx.x & 63;
    int j = w * 512 + u;
    float a0 = 0.f, a1 = 0.f, a2 = 0.f, a3 = 0.f;
    const float* Wr = &W_ih[(size_t)j * KX];
    for (int k = 0; k < KX; k += 4) {
        float4 wv = *reinterpret_cast<const float4*>(&Wr[k]);
        a0 += wv.x * xprevT[(k + 0) * 64 + b];
        a1 += wv.y * xprevT[(k + 1) * 64 + b];
        a2 += wv.z * xprevT[(k + 2) * 64 + b];
        a3 += wv.w * xprevT[(k + 3) * 64 + b];
    }
    const float* Wr2 = &W_hh[(size_t)j * H];
    const float* hT = &xprevT[KX * 64];
    for (int k = 0; k < H; k += 4) {
        float4 wv = *reinterpret_cast<const float4*>(&Wr2[k]);
        a0 += wv.x * hT[(k + 0) * 64 + b];
        a1 += wv.y * hT[(k + 1) * 64 + b];
        a2 += wv.z * hT[(k + 2) * 64 + b];
        a3 += wv.w * hT[(k + 3) * 64 + b];
    }
    float acc = b_ih[j] + b_hh[j] + ((a0 + a1) + (a2 + a3));
    __shared__ float gs[4][64];
    gs[w][b] = acc;
    __syncthreads();
    if (threadIdx.x < 64) {
        float ig = 1.f / (1.f + __expf(-gs[0][b]));
        float fg = 1.f / (1.f + __expf(-gs[1][b]));
        float gg = tanhf(gs[2][b]);
        float og = 1.f / (1.f + __expf(-gs[3][b]));
        float c = fg * cprev[b * H + u] + ig * gg;
        float h = og * tanhf(c);
        c_out[b * H + u] = c;
        h_out[b * H + u] = h;
        hnewT[u * 64 + b] = h;
    }
}

// ---------------------------------------------------------------------------
// K2: hW_jb[j][b] = b_attn[j] + sum_k h[b][k] * W_attn[j][k]
// ---------------------------------------------------------------------------
__global__ __launch_bounds__(256) void k_hw(const float* __restrict__ W_attn,
                                            const float* __restrict__ b_attn,
                                            const float* __restrict__ hT,
                                            float* __restrict__ hW_jb) {
    int j = blockIdx.x * 4 + (threadIdx.x >> 6);
    int b = threadIdx.x & 63;
    float a0 = 0.f, a1 = 0.f, a2 = 0.f, a3 = 0.f;
    const float* Wr = &W_attn[(size_t)j * (2 * H)];
    for (int k = 0; k < H; k += 4) {
        float4 wv = *reinterpret_cast<const float4*>(&Wr[k]);
        a0 += wv.x * hT[(k + 0) * 64 + b];
        a1 += wv.y * hT[(k + 1) * 64 + b];
        a2 += wv.z * hT[(k + 2) * 64 + b];
        a3 += wv.w * hT[(k + 3) * 64 + b];
    }
    hW_jb[j * 64 + b] = b_attn[j] + ((a0 + a1) + (a2 + a3));
}

// ---------------------------------------------------------------------------
// K3: energy, stage-A-once / stream-B.  Block = 64 m-rows (one l), all 512 j.
// A tile (64 x 512) staged to LDS fp16 ONCE; main loop has NO barriers:
// each wave owns 128 j, streams B fragments from global Wf (L1/L2-hot),
// accumulates acc[4 mf][8 nf], then psum over j in-block -> energy[m] direct.
// enc fetched exactly once (134 MB).  VGPR: acc 128 + frags ~50 < 256 cap.
// ---------------------------------------------------------------------------
#define EPITCH 520

__global__ __launch_bounds__(256, 2) void k_energy_v6(
        const float* __restrict__ enc,
        const unsigned short* __restrict__ Wf,
        const float* __restrict__ hW,
        const float* __restrict__ beta,
        float* __restrict__ energy) {
    __shared__ unsigned short As[64 * EPITCH];   // 66,560 B
    __shared__ float red[4][64];

    const int tid  = threadIdx.x;
    const int lane = tid & 63;
    const int w    = tid >> 6;          // wave 0..3 -> j range w*128
    const int m0   = blockIdx.x * 64;

    // ---- stage A once: 64 rows x 512 cols fp32 -> fp16 LDS ----
    {
        int row = tid >> 2;
        int kbase = (tid & 3) * 128;
        const float* src = &enc[(size_t)(m0 + row) * H + kbase];
        #pragma unroll
        for (int c = 0; c < 16; ++c) {
            float4 x0 = *reinterpret_cast<const float4*>(src + c * 8);
            float4 x1 = *reinterpret_cast<const float4*>(src + c * 8 + 4);
            half8v hv = cvt8(x0, x1);
            *reinterpret_cast<half8v*>(&As[row * EPITCH + kbase + c * 8]) = hv;
        }
    }
    __syncthreads();

    const int fr = lane & 15;
    const int kb = (lane >> 4) * 8;

    f32x4 acc[4][8];
    #pragma unroll
    for (int mf = 0; mf < 4; ++mf)
        #pragma unroll
        for (int nf = 0; nf < 8; ++nf) acc[mf][nf] = (f32x4){0.f, 0.f, 0.f, 0.f};

    const unsigned short* Bbase = &Wf[(size_t)(w * 128 + fr) * H + kb];

    for (int k0 = 0; k0 < H; k0 += 32) {
        half8v a_h[4];
        #pragma unroll
        for (int mf = 0; mf < 4; ++mf)
            a_h[mf] = *reinterpret_cast<const half8v*>(
                &As[(mf * 16 + fr) * EPITCH + k0 + kb]);
        #pragma unroll
        for (int nf = 0; nf < 8; ++nf) {
            half8v b_h = *reinterpret_cast<const half8v*>(&Bbase[(size_t)nf * 16 * H + k0]);
            #pragma unroll
            for (int mf = 0; mf < 4; ++mf)
                acc[mf][nf] = __builtin_amdgcn_mfma_f32_16x16x32_f16(
                    a_h[mf], b_h, acc[mf][nf], 0, 0, 0);
        }
    }

    // ---- epilogue: psum[mf][r] = sum_{nf, fr-col} tanh(C + hW)*beta ----
    float psum[4][4];
    #pragma unroll
    for (int i = 0; i < 4; ++i)
        #pragma unroll
        for (int r = 0; r < 4; ++r) psum[i][r] = 0.f;
    #pragma unroll
    for (int nf = 0; nf < 8; ++nf) {
        int jj = w * 128 + nf * 16 + fr;
        float bet = beta[jj];
        #pragma unroll
        for (int mf = 0; mf < 4; ++mf) {
            int b_base = mf * 16 + (lane >> 4) * 4;
            float4 hw4 = *reinterpret_cast<const float4*>(&hW[jj * 64 + b_base]);
            float hwv[4] = {hw4.x, hw4.y, hw4.z, hw4.w};
            #pragma unroll
            for (int r = 0; r < 4; ++r) {
                float e = acc[mf][nf][r] + hwv[r];
                float ex = __expf(2.f * e);
                psum[mf][r] += bet * (1.f - 2.f / (ex + 1.f));
            }
        }
    }
    // reduce over the 16 lanes (j axis) sharing each m
    #pragma unroll
    for (int mf = 0; mf < 4; ++mf)
        #pragma unroll
        for (int r = 0; r < 4; ++r) {
            float v = psum[mf][r];
            v += __shfl_xor(v, 1);
            v += __shfl_xor(v, 2);
            v += __shfl_xor(v, 4);
            v += __shfl_xor(v, 8);
            psum[mf][r] = v;
        }
    if (fr == 0) {
        #pragma unroll
        for (int mf = 0; mf < 4; ++mf)
            #pragma unroll
            for (int r = 0; r < 4; ++r)
                red[w][mf * 16 + (lane >> 4) * 4 + r] = psum[mf][r];
    }
    __syncthreads();
    if (tid < 64)
        energy[m0 + tid] = (red[0][tid] + red[1][tid]) + (red[2][tid] + red[3][tid]);
}

// ---------------------------------------------------------------------------
// K4: softmax over l per b.  energy[l*64+b]
// ---------------------------------------------------------------------------
__global__ __launch_bounds__(256) void k_softmax_l(const float* __restrict__ energy,
                                                   float* __restrict__ attn_w) {
    int b = blockIdx.x;
    int tid = threadIdx.x;
    float el[4];
    float m = -1e30f;
    #pragma unroll
    for (int i = 0; i < 4; ++i) {
        int l = i * 256 + tid;
        float e = energy[l * 64 + b];
        el[i] = e;
        m = fmaxf(m, e);
    }
    #pragma unroll
    for (int s = 1; s < 64; s <<= 1) m = fmaxf(m, __shfl_xor(m, s));
    __shared__ float redm[4];
    if ((tid & 63) == 0) redm[tid >> 6] = m;
    __syncthreads();
    m = fmaxf(fmaxf(redm[0], redm[1]), fmaxf(redm[2], redm[3]));
    float s = 0.f;
    #pragma unroll
    for (int i = 0; i < 4; ++i) { el[i] = __expf(el[i] - m); s += el[i]; }
    #pragma unroll
    for (int sh = 1; sh < 64; sh <<= 1) s += __shfl_xor(s, sh);
    __shared__ float reds[4];
    if ((tid & 63) == 0) reds[tid >> 6] = s;
    __syncthreads();
    s = reds[0] + reds[1] + reds[2] + reds[3];
    float inv = 1.f / s;
    #pragma unroll
    for (int i = 0; i < 4; ++i)
        attn_w[(i * 256 + tid) * 64 + b] = el[i] * inv;
}

// ---------------------------------------------------------------------------
// K5: context partials over l chunks. float4, 128 threads.
// ---------------------------------------------------------------------------
__global__ __launch_bounds__(128) void k_ctx_part(const float* __restrict__ attn_w,
                                                  const float* __restrict__ enc,
                                                  float* __restrict__ ctx_part) {
    int chunk = blockIdx.x, b = blockIdx.y;
    int h = threadIdx.x * 4;
    float4 acc = {0.f, 0.f, 0.f, 0.f};
    for (int i = 0; i < 32; ++i) {
        int l = chunk * 32 + i;
        float w = attn_w[l * 64 + b];
        float4 e4 = *reinterpret_cast<const float4*>(
            &enc[((size_t)l * 64 + b) * H + h]);
        acc.x += w * e4.x;
        acc.y += w * e4.y;
        acc.z += w * e4.z;
        acc.w += w * e4.w;
    }
    *reinterpret_cast<float4*>(&ctx_part[((size_t)(chunk * 64 + b)) * H + h]) = acc;
}

__global__ __launch_bounds__(256) void k_ctx_reduce(const float* __restrict__ ctx_part,
                                                    float* __restrict__ ctxT) {
    int gid = blockIdx.x * 256 + threadIdx.x;
    int b = gid >> 9, h = gid & 511;
    float s = 0.f;
    for (int c = 0; c < 32; ++c)
        s += ctx_part[((size_t)(c * 64 + b)) * H + h];
    ctxT[h * 64 + b] = s;
}

// ---------------------------------------------------------------------------
// K6: co[b][j] = tanh([h | ctx] . W_oc[j] + b_oc[j])
// ---------------------------------------------------------------------------
__global__ __launch_bounds__(256) void k_co(const float* __restrict__ W_oc,
                                            const float* __restrict__ b_oc,
                                            const float* __restrict__ hT,
                                            const float* __restrict__ ctxT,
                                            float* __restrict__ co_out) {
    int j = blockIdx.x * 4 + (threadIdx.x >> 6);
    int b = threadIdx.x & 63;
    float a0 = 0.f, a1 = 0.f, a2 = 0.f, a3 = 0.f;
    const float* Wr = &W_oc[(size_t)j * (2 * H)];
    for (int k = 0; k < H; k += 4) {
        float4 wv = *reinterpret_cast<const float4*>(&Wr[k]);
        a0 += wv.x * hT[(k + 0) * 64 + b];
        a1 += wv.y * hT[(k + 1) * 64 + b];
        a2 += wv.z * hT[(k + 2) * 64 + b];
        a3 += wv.w * hT[(k + 3) * 64 + b];
    }
    const float* Wr2 = Wr + H;
    for (int k = 0; k < H; k += 4) {
        float4 wv = *reinterpret_cast<const float4*>(&Wr2[k]);
        a0 += wv.x * ctxT[(k + 0) * 64 + b];
        a1 += wv.y * ctxT[(k + 1) * 64 + b];
        a2 += wv.z * ctxT[(k + 2) * 64 + b];
        a3 += wv.w * ctxT[(k + 3) * 64 + b];
    }
    co_out[b * H + j] = tanhf(b_oc[j] + ((a0 + a1) + (a2 + a3)));
}

// ---------------------------------------------------------------------------
// K7: logits, no-LDS no-barrier fp16 MFMA.  Block = 64 j; wave w owns 16 j
// (j = bid*64 + w*16 + fr), all 64 m.  Operands converted in-register:
// A (co) re-read from L2 per wave; B (W_out) read exactly once from HBM.
// ---------------------------------------------------------------------------
__global__ __launch_bounds__(256) void k_logits_v3(const float* __restrict__ co,
                                                   const float* __restrict__ W_out,
                                                   const float* __restrict__ b_out,
                                                   float* __restrict__ logits) {
    const int tid  = threadIdx.x;
    const int lane = tid & 63;
    const int w    = tid >> 6;
    const int fr   = lane & 15;
    const int kb   = (lane >> 4) * 8;
    const int j    = blockIdx.x * 64 + w * 16 + fr;

    f32x4 acc[4];
    #pragma unroll
    for (int mf = 0; mf < 4; ++mf) acc[mf] = (f32x4){0.f, 0.f, 0.f, 0.f};

    const float* Arow = &co[(size_t)fr * H + kb];
    const float* Brow = &W_out[(size_t)j * H + kb];

    for (int k0 = 0; k0 < H; k0 += 32) {
        float4 b0 = *reinterpret_cast<const float4*>(Brow + k0);
        float4 b1 = *reinterpret_cast<const float4*>(Brow + k0 + 4);
        half8v bh = cvt8(b0, b1);
        #pragma unroll
        for (int mf = 0; mf < 4; ++mf) {
            const float* ap = Arow + (size_t)mf * 16 * H + k0;
            float4 a0 = *reinterpret_cast<const float4*>(ap);
            float4 a1 = *reinterpret_cast<const float4*>(ap + 4);
            half8v ah = cvt8(a0, a1);
            acc[mf] = __builtin_amdgcn_mfma_f32_16x16x32_f16(ah, bh, acc[mf], 0, 0, 0);
        }
    }
    float bo = b_out[j];
    #pragma unroll
    for (int mf = 0; mf < 4; ++mf) {
        int mbase = mf * 16 + (lane >> 4) * 4;
        #pragma unroll
        for (int r = 0; r < 4; ++r)
            logits[(size_t)(mbase + r) * V + j] = acc[mf][r] + bo;
    }
}

// ---------------------------------------------------------------------------
// K8a: per-(b, chunk) partial max & expsum. grid (8 chunks, 64 b), 256 thr.
// ---------------------------------------------------------------------------
__global__ __launch_bounds__(256) void k_lsm_part(const float* __restrict__ logits,
                                                  float* __restrict__ pmax,
                                                  float* __restrict__ psum) {
    int chunk = blockIdx.x, b = blockIdx.y;
    int tid = threadIdx.x;
    const float* row = &logits[(size_t)b * V + chunk * 4000];
    float v[16];
    float m = -1e30f;
    #pragma unroll
    for (int t = 0; t < 16; ++t) {
        int i = t * 256 + tid;
        v[t] = (i < 4000) ? row[i] : -1e30f;
        m = fmaxf(m, v[t]);
    }
    #pragma unroll
    for (int s = 1; s < 64; s <<= 1) m = fmaxf(m, __shfl_xor(m, s));
    __shared__ float redm[4];
    if ((tid & 63) == 0) redm[tid >> 6] = m;
    __syncthreads();
    m = fmaxf(fmaxf(redm[0], redm[1]), fmaxf(redm[2], redm[3]));
    float s = 0.f;
    #pragma unroll
    for (int t = 0; t < 16; ++t) s += __expf(v[t] - m);
    #pragma unroll
    for (int sh = 1; sh < 64; sh <<= 1) s += __shfl_xor(s, sh);
    __shared__ float reds[4];
    if ((tid & 63) == 0) reds[tid >> 6] = s;
    __syncthreads();
    if (tid == 0) {
        pmax[chunk * 64 + b] = m;
        psum[chunk * 64 + b] = reds[0] + reds[1] + reds[2] + reds[3];
    }
}

// K8b: lse[b] = gmax + log(sum of rescaled partials). 1 block, 64 threads.
__global__ __launch_bounds__(64) void k_lsm_final(const float* __restrict__ pmax,
                                                  const float* __restrict__ psum,
                                                  float* __restrict__ lse) {
    int b = threadIdx.x;
    float m = -1e30f;
    #pragma unroll
    for (int c = 0; c < 8; ++c) m = fmaxf(m, pmax[c * 64 + b]);
    float s = 0.f;
    #pragma unroll
    for (int c = 0; c < 8; ++c) s += psum[c * 64 + b] * __expf(pmax[c * 64 + b] - m);
    lse[b] = m + __logf(s);
}

// K8c: out = logits - lse[b].  2000 blocks x 256 thr x 4 elems.
__global__ __launch_bounds__(256) void k_lsm_write(const float* __restrict__ logits,
                                                   const float* __restrict__ lse,
                                                   float* __restrict__ out) {
    size_t i4 = ((size_t)blockIdx.x * 256 + threadIdx.x) * 4;
    int b = (int)(i4 / V);
    float l = lse[b];
    float4 x = *reinterpret_cast<const float4*>(&logits[i4]);
    x.x -= l; x.y -= l; x.z -= l; x.w -= l;
    *reinterpret_cast<float4*>(&out[i4]) = x;
}

// ---------------------------------------------------------------------------
extern "C" void kernel_launch(void* const* d_in, const int* in_sizes, int n_in,
                              void* d_out, int out_size, void* d_ws, size_t ws_size,
                              hipStream_t stream) {
    const int*   inp    = (const int*)  d_in[0];
    const float* loc    = (const float*)d_in[1];
    const float* hprev  = (const float*)d_in[2];
    const float* cprev  = (const float*)d_in[3];
    const float* enc    = (const float*)d_in[4];
    const float* emb    = (const float*)d_in[5];
    const float* W_ih   = (const float*)d_in[6];
    const float* W_hh   = (const float*)d_in[7];
    const float* b_ih   = (const float*)d_in[8];
    const float* b_hh   = (const float*)d_in[9];
    const float* W_attn = (const float*)d_in[10];
    const float* b_attn = (const float*)d_in[11];
    const float* beta   = (const float*)d_in[12];
    const float* W_oc   = (const float*)d_in[13];
    const float* b_oc   = (const float*)d_in[14];
    const float* W_out  = (const float*)d_in[15];
    const float* b_out  = (const float*)d_in[16];

    float* out = (float*)d_out;
    float* out_co = out + (size_t)B * V;
    float* out_h  = out_co + B * H;
    float* out_c  = out_h  + B * H;

    float* ws = (float*)d_ws;
    float* xprevT = ws;                                  //    81920
    float* hnewT  = xprevT + 1280 * 64;                  //    32768
    float* hW     = hnewT  + H * 64;                     //    32768
    float* energy = hW     + H * 64;                     //    65536
    float* attnw  = energy + M_TOT;                      //    65536
    float* ctxp   = attnw  + M_TOT;                      //  1048576
    float* ctxT   = ctxp   + 32 * 64 * H;                //    32768
    float* logits = ctxT   + H * 64;                     //  2048000
    float* pmax   = logits + (size_t)B * V;              //      512
    float* psum   = pmax   + 512;                        //      512
    float* lse    = psum   + 512;                        //       64
    unsigned short* Wf = (unsigned short*)(lse + 64);    //   262144 u16

    k_conv_w<<<128, 256, 0, stream>>>(W_attn, Wf);
    k_build <<<320, 256, 0, stream>>>(inp, loc, hprev, emb, xprevT);
    k_lstm  <<<512, 256, 0, stream>>>(W_ih, W_hh, b_ih, b_hh, xprevT, cprev,
                                      out_h, out_c, hnewT);
    k_hw    <<<128, 256, 0, stream>>>(W_attn, b_attn, hnewT, hW);
    k_energy_v6<<<1024, 256, 0, stream>>>(enc, Wf, hW, beta, energy);
    k_softmax_l<<<64, 256, 0, stream>>>(energy, attnw);
    k_ctx_part <<<dim3(32, 64), 128, 0, stream>>>(attnw, enc, ctxp);
    k_ctx_reduce<<<128, 256, 0, stream>>>(ctxp, ctxT);
    k_co    <<<128, 256, 0, stream>>>(W_oc, b_oc, hnewT, ctxT, out_co);
    k_logits_v3<<<500, 256, 0, stream>>>(out_co, W_out, b_out, logits);
    k_lsm_part<<<dim3(8, 64), 256, 0, stream>>>(logits, pmax, psum);
    k_lsm_final<<<1, 64, 0, stream>>>(pmax, psum, lse);
    k_lsm_write<<<2000, 256, 0, stream>>>(logits, lse, out);
}

// Round 9
// 254.827 us; speedup vs baseline: 2.3215x; 1.2292x over previous
//
#include <hip/hip_runtime.h>
#include <hip/hip_bf16.h>
#include <cstddef>

// Problem dims
#define H   512
#define E   256
#define V   32000
#define L   1024
#define B   64
#define KX  768      // E + H
#define M_TOT 65536  // L*B

typedef __attribute__((ext_vector_type(8))) _Float16 half8v;
typedef __attribute__((ext_vector_type(4))) float f32x4;

__device__ __forceinline__ half8v cvt8(float4 x0, float4 x1) {
    union { half8v v; _Float16 u[8]; } hv;
    hv.u[0] = (_Float16)x0.x; hv.u[1] = (_Float16)x0.y;
    hv.u[2] = (_Float16)x0.z; hv.u[3] = (_Float16)x0.w;
    hv.u[4] = (_Float16)x1.x; hv.u[5] = (_Float16)x1.y;
    hv.u[6] = (_Float16)x1.z; hv.u[7] = (_Float16)x1.w;
    return hv.v;
}

// ---------------------------------------------------------------------------
// K-1: convert W_attn[:, H:] to fp16 once (512 KB out).
// ---------------------------------------------------------------------------
__global__ __launch_bounds__(256) void k_conv_w(const float* __restrict__ W_attn,
                                                unsigned short* __restrict__ Wf) {
    int e0 = blockIdx.x * 2048 + threadIdx.x * 8;      // 0..262143
    int j = e0 >> 9, k = e0 & 511;
    const float* src = &W_attn[(size_t)j * (2 * H) + H + k];
    float4 x0 = *reinterpret_cast<const float4*>(src);
    float4 x1 = *reinterpret_cast<const float4*>(src + 4);
    half8v hv = cvt8(x0, x1);
    *reinterpret_cast<half8v*>(&Wf[e0]) = hv;
}

// ---------------------------------------------------------------------------
// K0: build xprevT[k][b]
// ---------------------------------------------------------------------------
__global__ __launch_bounds__(256) void k_build(const int* __restrict__ inp,
                                               const float* __restrict__ loc,
                                               const float* __restrict__ hprev,
                                               const float* __restrict__ emb,
                                               float* __restrict__ xprevT) {
    int gid = blockIdx.x * 256 + threadIdx.x;
    int k = gid >> 6, b = gid & 63;
    float v;
    if (k < 256)      v = emb[(size_t)inp[b] * E + k];
    else if (k < 768) v = loc[b * H + (k - 256)];
    else              v = hprev[b * H + (k - 768)];
    xprevT[gid] = v;
}

// ---------------------------------------------------------------------------
// K1: LSTM cell (fp32)
// ---------------------------------------------------------------------------
__global__ __launch_bounds__(256) void k_lstm(const float* __restrict__ W_ih,
                                              const float* __restrict__ W_hh,
                                              const float* __restrict__ b_ih,
                                              const float* __restrict__ b_hh,
                                              const float* __restrict__ xprevT,
                                              const float* __restrict__ cprev,
                                              float* __restrict__ h_out,
                                              float* __restrict__ c_out,
                                              float* __restrict__ hnewT) {
    int u = blockIdx.x;
    int w = threadIdx.x >> 6;
    int b = threadIdx.x & 63;
    int j = w * 512 + u;
    float a0 = 0.f, a1 = 0.f, a2 = 0.f, a3 = 0.f;
    const float* Wr = &W_ih[(size_t)j * KX];
    for (int k = 0; k < KX; k += 4) {
        float4 wv = *reinterpret_cast<const float4*>(&Wr[k]);
        a0 += wv.x * xprevT[(k + 0) * 64 + b];
        a1 += wv.y * xprevT[(k + 1) * 64 + b];
        a2 += wv.z * xprevT[(k + 2) * 64 + b];
        a3 += wv.w * xprevT[(k + 3) * 64 + b];
    }
    const float* Wr2 = &W_hh[(size_t)j * H];
    const float* hT = &xprevT[KX * 64];
    for (int k = 0; k < H; k += 4) {
        float4 wv = *reinterpret_cast<const float4*>(&Wr2[k]);
        a0 += wv.x * hT[(k + 0) * 64 + b];
        a1 += wv.y * hT[(k + 1) * 64 + b];
        a2 += wv.z * hT[(k + 2) * 64 + b];
        a3 += wv.w * hT[(k + 3) * 64 + b];
    }
    float acc = b_ih[j] + b_hh[j] + ((a0 + a1) + (a2 + a3));
    __shared__ float gs[4][64];
    gs[w][b] = acc;
    __syncthreads();
    if (threadIdx.x < 64) {
        float ig = 1.f / (1.f + __expf(-gs[0][b]));
        float fg = 1.f / (1.f + __expf(-gs[1][b]));
        float gg = tanhf(gs[2][b]);
        float og = 1.f / (1.f + __expf(-gs[3][b]));
        float c = fg * cprev[b * H + u] + ig * gg;
        float h = og * tanhf(c);
        c_out[b * H + u] = c;
        h_out[b * H + u] = h;
        hnewT[u * 64 + b] = h;
    }
}

// ---------------------------------------------------------------------------
// K2: hW_jb[j][b] = b_attn[j] + sum_k h[b][k] * W_attn[j][k]
// ---------------------------------------------------------------------------
__global__ __launch_bounds__(256) void k_hw(const float* __restrict__ W_attn,
                                            const float* __restrict__ b_attn,
                                            const float* __restrict__ hT,
                                            float* __restrict__ hW_jb) {
    int j = blockIdx.x * 4 + (threadIdx.x >> 6);
    int b = threadIdx.x & 63;
    float a0 = 0.f, a1 = 0.f, a2 = 0.f, a3 = 0.f;
    const float* Wr = &W_attn[(size_t)j * (2 * H)];
    for (int k = 0; k < H; k += 4) {
        float4 wv = *reinterpret_cast<const float4*>(&Wr[k]);
        a0 += wv.x * hT[(k + 0) * 64 + b];
        a1 += wv.y * hT[(k + 1) * 64 + b];
        a2 += wv.z * hT[(k + 2) * 64 + b];
        a3 += wv.w * hT[(k + 3) * 64 + b];
    }
    hW_jb[j * 64 + b] = b_attn[j] + ((a0 + a1) + (a2 + a3));
}

// ---------------------------------------------------------------------------
// K3: energy GEMM (= R6's k_energy_v4 body, BK=32) + XCD-aware swizzle.
// grid 2048; xcd = bid&7 owns mt range [xcd*64, xcd*64+64); the 4 jt-siblings
// of one mt have bids 8 apart -> same XCD, adjacent in time -> A-tile L2 hit.
// Output: partial_e[jt][m] = sum_{j in tile} tanh(C+hW)*beta.
// ---------------------------------------------------------------------------
#define BKE 32
#define PITCH 40

__global__ __launch_bounds__(256, 4) void k_energy_v7(
        const float* __restrict__ enc,
        const unsigned short* __restrict__ Wf,
        const float* __restrict__ hW,
        const float* __restrict__ beta,
        float* __restrict__ partial_e) {
    __shared__ unsigned short Ah[128 * PITCH];
    __shared__ unsigned short Bh[128 * PITCH];
    __shared__ float red[2][128];

    const int tid  = threadIdx.x;
    const int lane = tid & 63;
    const int wave = tid >> 6;
    const int wm = wave >> 1;
    const int wn = wave & 1;
    // XCD-aware swizzle (bijective: 2048 = 8 * 256)
    const int bid = blockIdx.x;
    const int xcd = bid & 7;
    const int loc = bid >> 3;            // 0..255 within XCD
    const int mt  = xcd * 64 + (loc >> 2);
    const int jt  = loc & 3;
    const int m0 = mt * 128;
    const int j0 = jt * 128;

    const int srow = tid >> 2;          // 0..63
    const int skc  = tid & 3;           // 0..3 (8-elem chunk)

    float4 ra0[2], ra1[2];              // next A tile (fp32)
    half8v rb[2];                       // next B tile (fp16)
    #pragma unroll
    for (int p = 0; p < 2; ++p) {
        int row = p * 64 + srow;
        const float* asrc = &enc[(size_t)(m0 + row) * H + skc * 8];
        ra0[p] = *reinterpret_cast<const float4*>(asrc);
        ra1[p] = *reinterpret_cast<const float4*>(asrc + 4);
        rb[p] = *reinterpret_cast<const half8v*>(&Wf[(size_t)(j0 + row) * H + skc * 8]);
    }

    f32x4 acc[4][4];
    #pragma unroll
    for (int i = 0; i < 4; ++i)
        #pragma unroll
        for (int j = 0; j < 4; ++j) acc[i][j] = (f32x4){0.f, 0.f, 0.f, 0.f};

    for (int k0 = 0; k0 < H; k0 += BKE) {
        __syncthreads();                 // previous iter's reads done
        #pragma unroll
        for (int p = 0; p < 2; ++p) {
            half8v hv = cvt8(ra0[p], ra1[p]);
            int off = (p * 64 + srow) * PITCH + skc * 8;
            *reinterpret_cast<half8v*>(&Ah[off]) = hv;
            *reinterpret_cast<half8v*>(&Bh[off]) = rb[p];
        }
        __syncthreads();                 // writes visible
        if (k0 + BKE < H) {              // prefetch next tile under the MFMAs
            int kn = k0 + BKE;
            #pragma unroll
            for (int p = 0; p < 2; ++p) {
                int row = p * 64 + srow;
                const float* asrc = &enc[(size_t)(m0 + row) * H + kn + skc * 8];
                ra0[p] = *reinterpret_cast<const float4*>(asrc);
                ra1[p] = *reinterpret_cast<const float4*>(asrc + 4);
                rb[p] = *reinterpret_cast<const half8v*>(&Wf[(size_t)(j0 + row) * H + kn + skc * 8]);
            }
        }
        const int fr = lane & 15;
        const int kb = (lane >> 4) * 8;
        half8v a_h[4], b_h[4];
        #pragma unroll
        for (int mf = 0; mf < 4; ++mf) {
            int off = (wm * 64 + mf * 16 + fr) * PITCH + kb;
            a_h[mf] = *reinterpret_cast<const half8v*>(&Ah[off]);
        }
        #pragma unroll
        for (int nf = 0; nf < 4; ++nf) {
            int off = (wn * 64 + nf * 16 + fr) * PITCH + kb;
            b_h[nf] = *reinterpret_cast<const half8v*>(&Bh[off]);
        }
        #pragma unroll
        for (int mf = 0; mf < 4; ++mf)
            #pragma unroll
            for (int nf = 0; nf < 4; ++nf)
                acc[mf][nf] = __builtin_amdgcn_mfma_f32_16x16x32_f16(
                    a_h[mf], b_h[nf], acc[mf][nf], 0, 0, 0);
    }
    // epilogue: psum[mf][r] = sum_j tanh(C + hW)*beta
    float psum[4][4];
    #pragma unroll
    for (int i = 0; i < 4; ++i)
        #pragma unroll
        for (int r = 0; r < 4; ++r) psum[i][r] = 0.f;
    #pragma unroll
    for (int nf = 0; nf < 4; ++nf) {
        int jj = j0 + wn * 64 + nf * 16 + (lane & 15);
        float bet = beta[jj];
        #pragma unroll
        for (int mf = 0; mf < 4; ++mf) {
            int b_base = (wm * 64 + mf * 16 + (lane >> 4) * 4) & 63;
            float4 hw4 = *reinterpret_cast<const float4*>(&hW[jj * 64 + b_base]);
            float hwv[4] = {hw4.x, hw4.y, hw4.z, hw4.w};
            #pragma unroll
            for (int r = 0; r < 4; ++r) {
                float e = acc[mf][nf][r] + hwv[r];
                float ex = __expf(2.f * e);
                psum[mf][r] += bet * (1.f - 2.f / (ex + 1.f));
            }
        }
    }
    #pragma unroll
    for (int mf = 0; mf < 4; ++mf)
        #pragma unroll
        for (int r = 0; r < 4; ++r) {
            float v = psum[mf][r];
            v += __shfl_xor(v, 1);
            v += __shfl_xor(v, 2);
            v += __shfl_xor(v, 4);
            v += __shfl_xor(v, 8);
            psum[mf][r] = v;
        }
    __syncthreads();
    if ((lane & 15) == 0) {
        #pragma unroll
        for (int mf = 0; mf < 4; ++mf)
            #pragma unroll
            for (int r = 0; r < 4; ++r)
                red[wn][wm * 64 + mf * 16 + (lane >> 4) * 4 + r] = psum[mf][r];
    }
    __syncthreads();
    if (tid < 128)
        partial_e[(size_t)jt * M_TOT + m0 + tid] = red[0][tid] + red[1][tid];
}

// ---------------------------------------------------------------------------
// K4: softmax over l per b.  e[l] = sum_{nb<4} partial_e[nb][l*64+b]
// ---------------------------------------------------------------------------
__global__ __launch_bounds__(256) void k_softmax_l(const float* __restrict__ partial_e,
                                                   float* __restrict__ attn_w) {
    int b = blockIdx.x;
    int tid = threadIdx.x;
    float el[4];
    float m = -1e30f;
    #pragma unroll
    for (int i = 0; i < 4; ++i) {
        int l = i * 256 + tid;
        float e = 0.f;
        #pragma unroll
        for (int nb = 0; nb < 4; ++nb)
            e += partial_e[(size_t)nb * M_TOT + l * 64 + b];
        el[i] = e;
        m = fmaxf(m, e);
    }
    #pragma unroll
    for (int s = 1; s < 64; s <<= 1) m = fmaxf(m, __shfl_xor(m, s));
    __shared__ float redm[4];
    if ((tid & 63) == 0) redm[tid >> 6] = m;
    __syncthreads();
    m = fmaxf(fmaxf(redm[0], redm[1]), fmaxf(redm[2], redm[3]));
    float s = 0.f;
    #pragma unroll
    for (int i = 0; i < 4; ++i) { el[i] = __expf(el[i] - m); s += el[i]; }
    #pragma unroll
    for (int sh = 1; sh < 64; sh <<= 1) s += __shfl_xor(s, sh);
    __shared__ float reds[4];
    if ((tid & 63) == 0) reds[tid >> 6] = s;
    __syncthreads();
    s = reds[0] + reds[1] + reds[2] + reds[3];
    float inv = 1.f / s;
    #pragma unroll
    for (int i = 0; i < 4; ++i)
        attn_w[(i * 256 + tid) * 64 + b] = el[i] * inv;
}

// ---------------------------------------------------------------------------
// K5: context partials over l chunks. float4, 128 threads.
// ---------------------------------------------------------------------------
__global__ __launch_bounds__(128) void k_ctx_part(const float* __restrict__ attn_w,
                                                  const float* __restrict__ enc,
                                                  float* __restrict__ ctx_part) {
    int chunk = blockIdx.x, b = blockIdx.y;
    int h = threadIdx.x * 4;
    float4 acc = {0.f, 0.f, 0.f, 0.f};
    for (int i = 0; i < 32; ++i) {
        int l = chunk * 32 + i;
        float w = attn_w[l * 64 + b];
        float4 e4 = *reinterpret_cast<const float4*>(
            &enc[((size_t)l * 64 + b) * H + h]);
        acc.x += w * e4.x;
        acc.y += w * e4.y;
        acc.z += w * e4.z;
        acc.w += w * e4.w;
    }
    *reinterpret_cast<float4*>(&ctx_part[((size_t)(chunk * 64 + b)) * H + h]) = acc;
}

__global__ __launch_bounds__(256) void k_ctx_reduce(const float* __restrict__ ctx_part,
                                                    float* __restrict__ ctxT) {
    int gid = blockIdx.x * 256 + threadIdx.x;
    int b = gid >> 9, h = gid & 511;
    float s = 0.f;
    for (int c = 0; c < 32; ++c)
        s += ctx_part[((size_t)(c * 64 + b)) * H + h];
    ctxT[h * 64 + b] = s;
}

// ---------------------------------------------------------------------------
// K6: co[b][j] = tanh([h | ctx] . W_oc[j] + b_oc[j])
// ---------------------------------------------------------------------------
__global__ __launch_bounds__(256) void k_co(const float* __restrict__ W_oc,
                                            const float* __restrict__ b_oc,
                                            const float* __restrict__ hT,
                                            const float* __restrict__ ctxT,
                                            float* __restrict__ co_out) {
    int j = blockIdx.x * 4 + (threadIdx.x >> 6);
    int b = threadIdx.x & 63;
    float a0 = 0.f, a1 = 0.f, a2 = 0.f, a3 = 0.f;
    const float* Wr = &W_oc[(size_t)j * (2 * H)];
    for (int k = 0; k < H; k += 4) {
        float4 wv = *reinterpret_cast<const float4*>(&Wr[k]);
        a0 += wv.x * hT[(k + 0) * 64 + b];
        a1 += wv.y * hT[(k + 1) * 64 + b];
        a2 += wv.z * hT[(k + 2) * 64 + b];
        a3 += wv.w * hT[(k + 3) * 64 + b];
    }
    const float* Wr2 = Wr + H;
    for (int k = 0; k < H; k += 4) {
        float4 wv = *reinterpret_cast<const float4*>(&Wr2[k]);
        a0 += wv.x * ctxT[(k + 0) * 64 + b];
        a1 += wv.y * ctxT[(k + 1) * 64 + b];
        a2 += wv.z * ctxT[(k + 2) * 64 + b];
        a3 += wv.w * ctxT[(k + 3) * 64 + b];
    }
    co_out[b * H + j] = tanhf(b_oc[j] + ((a0 + a1) + (a2 + a3)));
}

// ---------------------------------------------------------------------------
// K7: logits, no-LDS no-barrier fp16 MFMA (R8 version, kept).
// ---------------------------------------------------------------------------
__global__ __launch_bounds__(256) void k_logits_v3(const float* __restrict__ co,
                                                   const float* __restrict__ W_out,
                                                   const float* __restrict__ b_out,
                                                   float* __restrict__ logits) {
    const int tid  = threadIdx.x;
    const int lane = tid & 63;
    const int w    = tid >> 6;
    const int fr   = lane & 15;
    const int kb   = (lane >> 4) * 8;
    const int j    = blockIdx.x * 64 + w * 16 + fr;

    f32x4 acc[4];
    #pragma unroll
    for (int mf = 0; mf < 4; ++mf) acc[mf] = (f32x4){0.f, 0.f, 0.f, 0.f};

    const float* Arow = &co[(size_t)fr * H + kb];
    const float* Brow = &W_out[(size_t)j * H + kb];

    for (int k0 = 0; k0 < H; k0 += 32) {
        float4 b0 = *reinterpret_cast<const float4*>(Brow + k0);
        float4 b1 = *reinterpret_cast<const float4*>(Brow + k0 + 4);
        half8v bh = cvt8(b0, b1);
        #pragma unroll
        for (int mf = 0; mf < 4; ++mf) {
            const float* ap = Arow + (size_t)mf * 16 * H + k0;
            float4 a0 = *reinterpret_cast<const float4*>(ap);
            float4 a1 = *reinterpret_cast<const float4*>(ap + 4);
            half8v ah = cvt8(a0, a1);
            acc[mf] = __builtin_amdgcn_mfma_f32_16x16x32_f16(ah, bh, acc[mf], 0, 0, 0);
        }
    }
    float bo = b_out[j];
    #pragma unroll
    for (int mf = 0; mf < 4; ++mf) {
        int mbase = mf * 16 + (lane >> 4) * 4;
        #pragma unroll
        for (int r = 0; r < 4; ++r)
            logits[(size_t)(mbase + r) * V + j] = acc[mf][r] + bo;
    }
}

// ---------------------------------------------------------------------------
// K8a: per-(b, chunk) partial max & expsum. grid (8 chunks, 64 b), 256 thr.
// ---------------------------------------------------------------------------
__global__ __launch_bounds__(256) void k_lsm_part(const float* __restrict__ logits,
                                                  float* __restrict__ pmax,
                                                  float* __restrict__ psum) {
    int chunk = blockIdx.x, b = blockIdx.y;
    int tid = threadIdx.x;
    const float* row = &logits[(size_t)b * V + chunk * 4000];
    float v[16];
    float m = -1e30f;
    #pragma unroll
    for (int t = 0; t < 16; ++t) {
        int i = t * 256 + tid;
        v[t] = (i < 4000) ? row[i] : -1e30f;
        m = fmaxf(m, v[t]);
    }
    #pragma unroll
    for (int s = 1; s < 64; s <<= 1) m = fmaxf(m, __shfl_xor(m, s));
    __shared__ float redm[4];
    if ((tid & 63) == 0) redm[tid >> 6] = m;
    __syncthreads();
    m = fmaxf(fmaxf(redm[0], redm[1]), fmaxf(redm[2], redm[3]));
    float s = 0.f;
    #pragma unroll
    for (int t = 0; t < 16; ++t) s += __expf(v[t] - m);
    #pragma unroll
    for (int sh = 1; sh < 64; sh <<= 1) s += __shfl_xor(s, sh);
    __shared__ float reds[4];
    if ((tid & 63) == 0) reds[tid >> 6] = s;
    __syncthreads();
    if (tid == 0) {
        pmax[chunk * 64 + b] = m;
        psum[chunk * 64 + b] = reds[0] + reds[1] + reds[2] + reds[3];
    }
}

// K8b: lse[b] = gmax + log(sum of rescaled partials). 1 block, 64 threads.
__global__ __launch_bounds__(64) void k_lsm_final(const float* __restrict__ pmax,
                                                  const float* __restrict__ psum,
                                                  float* __restrict__ lse) {
    int b = threadIdx.x;
    float m = -1e30f;
    #pragma unroll
    for (int c = 0; c < 8; ++c) m = fmaxf(m, pmax[c * 64 + b]);
    float s = 0.f;
    #pragma unroll
    for (int c = 0; c < 8; ++c) s += psum[c * 64 + b] * __expf(pmax[c * 64 + b] - m);
    lse[b] = m + __logf(s);
}

// K8c: out = logits - lse[b].  2000 blocks x 256 thr x 4 elems.
__global__ __launch_bounds__(256) void k_lsm_write(const float* __restrict__ logits,
                                                   const float* __restrict__ lse,
                                                   float* __restrict__ out) {
    size_t i4 = ((size_t)blockIdx.x * 256 + threadIdx.x) * 4;
    int b = (int)(i4 / V);
    float l = lse[b];
    float4 x = *reinterpret_cast<const float4*>(&logits[i4]);
    x.x -= l; x.y -= l; x.z -= l; x.w -= l;
    *reinterpret_cast<float4*>(&out[i4]) = x;
}

// ---------------------------------------------------------------------------
extern "C" void kernel_launch(void* const* d_in, const int* in_sizes, int n_in,
                              void* d_out, int out_size, void* d_ws, size_t ws_size,
                              hipStream_t stream) {
    const int*   inp    = (const int*)  d_in[0];
    const float* loc    = (const float*)d_in[1];
    const float* hprev  = (const float*)d_in[2];
    const float* cprev  = (const float*)d_in[3];
    const float* enc    = (const float*)d_in[4];
    const float* emb    = (const float*)d_in[5];
    const float* W_ih   = (const float*)d_in[6];
    const float* W_hh   = (const float*)d_in[7];
    const float* b_ih   = (const float*)d_in[8];
    const float* b_hh   = (const float*)d_in[9];
    const float* W_attn = (const float*)d_in[10];
    const float* b_attn = (const float*)d_in[11];
    const float* beta   = (const float*)d_in[12];
    const float* W_oc   = (const float*)d_in[13];
    const float* b_oc   = (const float*)d_in[14];
    const float* W_out  = (const float*)d_in[15];
    const float* b_out  = (const float*)d_in[16];

    float* out = (float*)d_out;
    float* out_co = out + (size_t)B * V;
    float* out_h  = out_co + B * H;
    float* out_c  = out_h  + B * H;

    float* ws = (float*)d_ws;
    float* xprevT = ws;                                  //    81920
    float* hnewT  = xprevT + 1280 * 64;                  //    32768
    float* hW     = hnewT  + H * 64;                     //    32768
    float* pe     = hW     + H * 64;                     //  4*65536
    float* attnw  = pe     + 4 * M_TOT;                  //    65536
    float* ctxp   = attnw  + M_TOT;                      //  1048576
    float* ctxT   = ctxp   + 32 * 64 * H;                //    32768
    float* logits = ctxT   + H * 64;                     //  2048000
    float* pmax   = logits + (size_t)B * V;              //      512
    float* psum   = pmax   + 512;                        //      512
    float* lse    = psum   + 512;                        //       64
    unsigned short* Wf = (unsigned short*)(lse + 64);    //   262144 u16

    k_conv_w<<<128, 256, 0, stream>>>(W_attn, Wf);
    k_build <<<320, 256, 0, stream>>>(inp, loc, hprev, emb, xprevT);
    k_lstm  <<<512, 256, 0, stream>>>(W_ih, W_hh, b_ih, b_hh, xprevT, cprev,
                                      out_h, out_c, hnewT);
    k_hw    <<<128, 256, 0, stream>>>(W_attn, b_attn, hnewT, hW);
    k_energy_v7<<<2048, 256, 0, stream>>>(enc, Wf, hW, beta, pe);
    k_softmax_l<<<64, 256, 0, stream>>>(pe, attnw);
    k_ctx_part <<<dim3(32, 64), 128, 0, stream>>>(attnw, enc, ctxp);
    k_ctx_reduce<<<128, 256, 0, stream>>>(ctxp, ctxT);
    k_co    <<<128, 256, 0, stream>>>(W_oc, b_oc, hnewT, ctxT, out_co);
    k_logits_v3<<<500, 256, 0, stream>>>(out_co, W_out, b_out, logits);
    k_lsm_part<<<dim3(8, 64), 256, 0, stream>>>(logits, pmax, psum);
    k_lsm_final<<<1, 64, 0, stream>>>(pmax, psum, lse);
    k_lsm_write<<<2000, 256, 0, stream>>>(logits, lse, out);
}